// Round 1
// baseline (108.133 us; speedup 1.0000x reference)
//
#include <hip/hip_runtime.h>
#include <math.h>

// Problem constants (B folded into N; all indexing is B*N-flat)
constexpr int KNB = 16;  // neighbors
constexpr int HH  = 4;   // heads
constexpr int DD  = 32;  // head dim

// One 32-lane half-wave per (n,h) group. 256-thread block = 8 groups.
// Lane index doubles as d (input dim) and e (output dim of the Linear).
__global__ __launch_bounds__(256) void geoneigh_kernel(
    const float* __restrict__ q,
    const float* __restrict__ kn,
    const float* __restrict__ vn,
    const float* __restrict__ geo,
    const float* __restrict__ W,
    const float* __restrict__ bvec,
    const float* __restrict__ gamma,
    const float* __restrict__ beta,
    float* __restrict__ out,
    int nGroups)   // (B*N)*H
{
    __shared__ float4 wbuf[8][8];  // one 32-float row per group

    const int tid  = threadIdx.x;
    const int g    = tid >> 5;   // group within block (0..7); groups 2g,2g+1 share a wave
    const int lane = tid & 31;   // d / e index
    const int gid  = blockIdx.x * 8 + g;
    if (gid >= nGroups) return;
    const int n = gid >> 2;      // node (B*N flat)
    const int h = gid & 3;       // head

    // Stage this lane's Linear row: lin[e=lane] = sum_d W[e*32+d] * w[d]
    float Wr[32];
    #pragma unroll
    for (int c = 0; c < 8; ++c) {
        const float4 w4 = *reinterpret_cast<const float4*>(&W[lane * DD + c * 4]);
        Wr[c * 4 + 0] = w4.x; Wr[c * 4 + 1] = w4.y;
        Wr[c * 4 + 2] = w4.z; Wr[c * 4 + 3] = w4.w;
    }
    const float bias = bvec[lane];
    const float gam  = gamma[lane];
    const float bet  = beta[lane];

    // reference: w = (q - k + geo) / (D**-0.5)  ==  * sqrt(D)
    const float scale = 5.656854249492381f;  // sqrt(32)

    const float qv = q[(n * HH + h) * DD + lane];

    const float* knp = kn  + ((size_t)n * KNB * HH + h) * DD + lane; // + k*HH*DD
    const float* gp  = geo + (size_t)n * KNB * DD + lane;            // + k*DD

    float wln[KNB];

    // simple software pipeline on the two per-k loads
    float kv = knp[0];
    float gv = gp[0];
    #pragma unroll
    for (int k = 0; k < KNB; ++k) {
        float kv_n = 0.f, gv_n = 0.f;
        if (k + 1 < KNB) {
            kv_n = knp[(k + 1) * (HH * DD)];
            gv_n = gp[(k + 1) * DD];
        }
        const float wv = (qv - kv + gv) * scale;

        // Broadcast w[0..31] to all lanes of the group via LDS.
        // Both half-waves of a wave write disjoint rows; same-wave DS ops
        // execute in order, so no barrier is needed (wave_barrier only pins
        // the compiler's ordering).
        reinterpret_cast<float*>(&wbuf[g][0])[lane] = wv;
        __builtin_amdgcn_wave_barrier();

        float acc = 0.f;
        #pragma unroll
        for (int c = 0; c < 8; ++c) {
            const float4 wc = wbuf[g][c];   // uniform address -> broadcast read
            acc = fmaf(Wr[c * 4 + 0], wc.x, acc);
            acc = fmaf(Wr[c * 4 + 1], wc.y, acc);
            acc = fmaf(Wr[c * 4 + 2], wc.z, acc);
            acc = fmaf(Wr[c * 4 + 3], wc.w, acc);
        }
        __builtin_amdgcn_wave_barrier();

        const float r = fmaxf(acc + bias, 0.f);  // +b, ReLU

        // LayerNorm over the 32 lanes (e dim)
        float s1 = r, s2 = r * r;
        #pragma unroll
        for (int m = 1; m < 32; m <<= 1) {
            s1 += __shfl_xor(s1, m, 32);
            s2 += __shfl_xor(s2, m, 32);
        }
        const float mu  = s1 * (1.0f / 32.0f);
        const float var = fmaxf(s2 * (1.0f / 32.0f) - mu * mu, 0.f);
        const float inv = rsqrtf(var + 1e-5f);
        wln[k] = (r - mu) * inv * gam + bet;

        kv = kv_n; gv = gv_n;
    }

    // Softmax over K, fully in-register (max-subtract == reference's
    // detached-max shift + softmax's own stabilization)
    float mx = wln[0];
    #pragma unroll
    for (int k = 1; k < KNB; ++k) mx = fmaxf(mx, wln[k]);
    float s = 0.f;
    #pragma unroll
    for (int k = 0; k < KNB; ++k) { wln[k] = __expf(wln[k] - mx); s += wln[k]; }
    const float invs = 1.0f / s;

    // out[n,h,e] = sum_k attn[k] * v[n,k,h,e]
    const float* vp = vn + ((size_t)n * KNB * HH + h) * DD + lane;
    float o = 0.f;
    #pragma unroll
    for (int k = 0; k < KNB; ++k) o = fmaf(wln[k], vp[k * (HH * DD)], o);

    out[(n * HH + h) * DD + lane] = o * invs;
}

extern "C" void kernel_launch(void* const* d_in, const int* in_sizes, int n_in,
                              void* d_out, int out_size, void* d_ws, size_t ws_size,
                              hipStream_t stream) {
    const float* q   = (const float*)d_in[0];
    const float* kn  = (const float*)d_in[1];
    const float* vn  = (const float*)d_in[2];
    const float* geo = (const float*)d_in[3];
    const float* W   = (const float*)d_in[4];
    const float* b   = (const float*)d_in[5];
    const float* gam = (const float*)d_in[6];
    const float* bet = (const float*)d_in[7];
    float* out = (float*)d_out;

    const int BN      = in_sizes[0] / (HH * DD);  // B*N
    const int nGroups = BN * HH;
    const int blocks  = (nGroups + 7) / 8;

    hipLaunchKernelGGL(geoneigh_kernel, dim3(blocks), dim3(256), 0, stream,
                       q, kn, vn, geo, W, b, gam, bet, out, nGroups);
}

// Round 2
// 104.875 us; speedup vs baseline: 1.0311x; 1.0311x over previous
//
#include <hip/hip_runtime.h>
#include <math.h>

// Problem constants (B folded into N; all indexing is B*N-flat)
constexpr int KNB = 16;  // neighbors
constexpr int HH  = 4;   // heads
constexpr int DD  = 32;  // head dim

// One 32-lane half-wave per (n,h) group. 256-thread block = 8 groups.
// Lane index doubles as d (input dim) and e (output dim of the Linear).
// Phased structure: all 16 neighbors in flight simultaneously for ILP.
__global__ __launch_bounds__(256) void geoneigh_kernel(
    const float* __restrict__ q,
    const float* __restrict__ kn,
    const float* __restrict__ vn,
    const float* __restrict__ geo,
    const float* __restrict__ W,
    const float* __restrict__ bvec,
    const float* __restrict__ gamma,
    const float* __restrict__ beta,
    float* __restrict__ out,
    int nGroups)   // (B*N)*H
{
    __shared__ float wbuf[8][KNB][DD];  // 16 KB: per-group 16x32 w rows

    const int tid  = threadIdx.x;
    const int g    = tid >> 5;   // group within block (0..7)
    const int lane = tid & 31;   // d / e index
    const int gid  = blockIdx.x * 8 + g;
    if (gid >= nGroups) return;  // no __syncthreads anywhere -> safe
    const int n = gid >> 2;      // node (B*N flat)
    const int h = gid & 3;       // head

    // This lane's Linear row: lin[e=lane] = sum_d W[e*32+d] * w[d]
    float Wr[32];
    #pragma unroll
    for (int c = 0; c < 8; ++c) {
        const float4 w4 = *reinterpret_cast<const float4*>(&W[lane * DD + c * 4]);
        Wr[c * 4 + 0] = w4.x; Wr[c * 4 + 1] = w4.y;
        Wr[c * 4 + 2] = w4.z; Wr[c * 4 + 3] = w4.w;
    }
    const float bias = bvec[lane];
    const float gam  = gamma[lane];
    const float bet  = beta[lane];

    const float scale = 5.656854249492381f;  // sqrt(32): w=(q-k+geo)/D**-0.5
    const float qv = q[(n * HH + h) * DD + lane];

    const float* knp = kn  + ((size_t)n * KNB * HH + h) * DD + lane;
    const float* gp  = geo + (size_t)n * KNB * DD + lane;

    // ---- Phase 1: all 32 loads in flight, compute w rows, stage to LDS ----
    float wv[KNB];
    #pragma unroll
    for (int k = 0; k < KNB; ++k) {
        const float kv = knp[k * (HH * DD)];
        const float gv = gp[k * DD];
        wv[k] = (qv - kv + gv) * scale;
    }
    #pragma unroll
    for (int k = 0; k < KNB; ++k) wbuf[g][k][lane] = wv[k];
    // Same-wave LDS ops are in program order; wave_barrier pins compiler order.
    __builtin_amdgcn_wave_barrier();

    // ---- Phase 2: Linear, 16 independent accumulator chains ----
    float acc[KNB];
    #pragma unroll
    for (int k = 0; k < KNB; ++k) acc[k] = 0.f;
    #pragma unroll
    for (int c = 0; c < 8; ++c) {
        const float w0 = Wr[c * 4 + 0], w1 = Wr[c * 4 + 1];
        const float w2 = Wr[c * 4 + 2], w3 = Wr[c * 4 + 3];
        #pragma unroll
        for (int k = 0; k < KNB; ++k) {
            const float4 wc = *reinterpret_cast<const float4*>(&wbuf[g][k][c * 4]);
            float a = acc[k];
            a = fmaf(w0, wc.x, a);
            a = fmaf(w1, wc.y, a);
            a = fmaf(w2, wc.z, a);
            a = fmaf(w3, wc.w, a);
            acc[k] = a;
        }
    }

    // ---- Phase 3: bias+ReLU+LayerNorm, 16 interleaved shuffle reductions ----
    float wln[KNB];
    #pragma unroll
    for (int k = 0; k < KNB; ++k) {
        const float r = fmaxf(acc[k] + bias, 0.f);
        float s1 = r, s2 = r * r;
        #pragma unroll
        for (int m = 1; m < 32; m <<= 1) {
            s1 += __shfl_xor(s1, m, 32);
            s2 += __shfl_xor(s2, m, 32);
        }
        const float mu  = s1 * (1.0f / 32.0f);
        const float var = fmaxf(s2 * (1.0f / 32.0f) - mu * mu, 0.f);
        const float inv = rsqrtf(var + 1e-5f);
        wln[k] = (r - mu) * inv * gam + bet;
    }

    // ---- Phase 4: softmax over K (in-register) + weighted V sum ----
    float mx = wln[0];
    #pragma unroll
    for (int k = 1; k < KNB; ++k) mx = fmaxf(mx, wln[k]);
    float s = 0.f;
    #pragma unroll
    for (int k = 0; k < KNB; ++k) { wln[k] = __expf(wln[k] - mx); s += wln[k]; }
    const float invs = 1.0f / s;

    const float* vp = vn + ((size_t)n * KNB * HH + h) * DD + lane;
    float o = 0.f;
    #pragma unroll
    for (int k = 0; k < KNB; ++k) o = fmaf(wln[k], vp[k * (HH * DD)], o);

    out[(n * HH + h) * DD + lane] = o * invs;
}

extern "C" void kernel_launch(void* const* d_in, const int* in_sizes, int n_in,
                              void* d_out, int out_size, void* d_ws, size_t ws_size,
                              hipStream_t stream) {
    const float* q   = (const float*)d_in[0];
    const float* kn  = (const float*)d_in[1];
    const float* vn  = (const float*)d_in[2];
    const float* geo = (const float*)d_in[3];
    const float* W   = (const float*)d_in[4];
    const float* b   = (const float*)d_in[5];
    const float* gam = (const float*)d_in[6];
    const float* bet = (const float*)d_in[7];
    float* out = (float*)d_out;

    const int BN      = in_sizes[0] / (HH * DD);  // B*N
    const int nGroups = BN * HH;
    const int blocks  = (nGroups + 7) / 8;

    hipLaunchKernelGGL(geoneigh_kernel, dim3(blocks), dim3(256), 0, stream,
                       q, kn, vn, geo, W, b, gam, bet, out, nGroups);
}

// Round 3
// 66.900 us; speedup vs baseline: 1.6164x; 1.5677x over previous
//
#include <hip/hip_runtime.h>
#include <math.h>

constexpr int KNB = 16;  // neighbors (K)
constexpr int HH  = 4;   // heads
constexpr int DD  = 32;  // head dim

typedef __attribute__((ext_vector_type(4))) float f32x4;
typedef __attribute__((ext_vector_type(8))) short bf16x8;  // 8 bf16 in 4 VGPRs
typedef __attribute__((ext_vector_type(4))) short s16x4;   // 8-byte LDS store

__device__ __forceinline__ unsigned short f2bf(float f) {
    union { float f; unsigned u; } v; v.f = f;
    const unsigned r = v.u + 0x7fffu + ((v.u >> 16) & 1u);  // RNE
    return (unsigned short)(r >> 16);
}
__device__ __forceinline__ float bf2f(unsigned short b) {
    union { unsigned u; float f; } v; v.u = ((unsigned)b) << 16; return v.f;
}

// One wave64 per TWO (n,h) units (same n, h-pair -> geo shared).
// Linear done as MFMA: lin[16 edges][32 e] = w(16x32) @ W^T(32x32),
// hi/lo bf16 split of both operands => fp32-level accuracy.
__global__ __launch_bounds__(256) void geoneigh_mfma(
    const float* __restrict__ q, const float* __restrict__ kn,
    const float* __restrict__ vn, const float* __restrict__ geo,
    const float* __restrict__ W, const float* __restrict__ bvec,
    const float* __restrict__ gamma, const float* __restrict__ beta,
    float* __restrict__ out, int BN)
{
    __shared__ short wt[4][2][2][16][32];  // [wave][unit][hi/lo][edge][d] bf16, 16 KB

    const int l  = threadIdx.x & 63;
    const int wv = threadIdx.x >> 6;
    const int gw = blockIdx.x * 4 + wv;
    const int n  = gw >> 1;
    if (n >= BN) return;               // no __syncthreads anywhere -> safe
    const int h0 = (gw & 1) * 2;

    const int lm = l & 15;   // 16-col index: e-low for B/C frags, edge for A frag
    const int lg = l >> 4;   // lane group 0..3 (k-block for A/B, edge-row-block for C)
    const int r8 = l >> 3;   // staging row 0..7
    const int dq = l & 7;    // staging d-quad

    // ---- B operand = W^T in registers: lane holds W[e=lm+16t][d=lg*8+j] ----
    bf16x8 Wh[2], Wl[2];
    #pragma unroll
    for (int t = 0; t < 2; ++t) {
        const float* wr = &W[(t * 16 + lm) * DD + lg * 8];
        const float4 a = *(const float4*)wr;
        const float4 b = *(const float4*)(wr + 4);
        const float wf[8] = {a.x, a.y, a.z, a.w, b.x, b.y, b.z, b.w};
        #pragma unroll
        for (int j = 0; j < 8; ++j) {
            const unsigned short h = f2bf(wf[j]);
            Wh[t][j] = (short)h;
            Wl[t][j] = (short)f2bf(wf[j] - bf2f(h));
        }
    }
    float bias[2], gam[2], bet[2];
    #pragma unroll
    for (int t = 0; t < 2; ++t) {
        bias[t] = bvec[lm + 16 * t];
        gam[t]  = gamma[lm + 16 * t];
        bet[t]  = beta[lm + 16 * t];
    }

    const float SC = 5.656854249492381f;  // sqrt(32): w=(q-k+geo)/D**-0.5

    // ---- vectorized global loads (dwordx4) ----
    float4 g4[2], q4[2], k4[2][2];
    #pragma unroll
    for (int j = 0; j < 2; ++j)
        g4[j] = *(const float4*)&geo[((size_t)n * KNB + r8 + 8 * j) * DD + dq * 4];
    #pragma unroll
    for (int u = 0; u < 2; ++u) {
        const int h = h0 + u;
        q4[u] = *(const float4*)&q[((size_t)n * HH + h) * DD + dq * 4];
        #pragma unroll
        for (int j = 0; j < 2; ++j)
            k4[u][j] = *(const float4*)&kn[(((size_t)n * KNB + r8 + 8 * j) * HH + h) * DD + dq * 4];
    }

    // ---- compute w rows, hi/lo bf16 split, stage A-tiles to LDS ----
    #pragma unroll
    for (int u = 0; u < 2; ++u) {
        #pragma unroll
        for (int j = 0; j < 2; ++j) {
            const int row = r8 + 8 * j;
            const float w0 = (q4[u].x - k4[u][j].x + g4[j].x) * SC;
            const float w1 = (q4[u].y - k4[u][j].y + g4[j].y) * SC;
            const float w2 = (q4[u].z - k4[u][j].z + g4[j].z) * SC;
            const float w3 = (q4[u].w - k4[u][j].w + g4[j].w) * SC;
            const unsigned short a0 = f2bf(w0), a1 = f2bf(w1), a2 = f2bf(w2), a3 = f2bf(w3);
            const s16x4 hi = {(short)a0, (short)a1, (short)a2, (short)a3};
            const s16x4 lo = {(short)f2bf(w0 - bf2f(a0)), (short)f2bf(w1 - bf2f(a1)),
                              (short)f2bf(w2 - bf2f(a2)), (short)f2bf(w3 - bf2f(a3))};
            *(s16x4*)&wt[wv][u][0][row][dq * 4] = hi;
            *(s16x4*)&wt[wv][u][1][row][dq * 4] = lo;
        }
    }
    asm volatile("" ::: "memory");  // pin LDS write->read ordering (same wave)

    // ---- A fragments: lane holds w[edge=lm][d=lg*8+j] ----
    bf16x8 Ah[2], Al[2];
    #pragma unroll
    for (int u = 0; u < 2; ++u) {
        Ah[u] = *(const bf16x8*)&wt[wv][u][0][lm][lg * 8];
        Al[u] = *(const bf16x8*)&wt[wv][u][1][lm][lg * 8];
    }

    // ---- V gather (needed after softmax; issue early to hide HBM latency) ----
    float vreg[2][2][4];  // [unit][e-half][reg]
    #pragma unroll
    for (int u = 0; u < 2; ++u)
        #pragma unroll
        for (int t = 0; t < 2; ++t)
            #pragma unroll
            for (int r = 0; r < 4; ++r)
                vreg[u][t][r] =
                    vn[(((size_t)n * KNB + lg * 4 + r) * HH + h0 + u) * DD + lm + 16 * t];

    // ---- MFMA: acc[u][t] = wh@Wh + wh@Wl + wl@Wh ----
    f32x4 acc[2][2];
    #pragma unroll
    for (int u = 0; u < 2; ++u)
        #pragma unroll
        for (int t = 0; t < 2; ++t) {
            f32x4 c = {0.f, 0.f, 0.f, 0.f};
            c = __builtin_amdgcn_mfma_f32_16x16x32_bf16(Ah[u], Wh[t], c, 0, 0, 0);
            c = __builtin_amdgcn_mfma_f32_16x16x32_bf16(Ah[u], Wl[t], c, 0, 0, 0);
            c = __builtin_amdgcn_mfma_f32_16x16x32_bf16(Al[u], Wh[t], c, 0, 0, 0);
            acc[u][t] = c;
        }

    // ---- per-unit epilogue: ReLU+LN (over e), softmax (over k), PV ----
    // C layout: lane holds C[edge=lg*4+r][e=lm+16t] for r=0..3, t=0..1
    #pragma unroll
    for (int u = 0; u < 2; ++u) {
        float x[2][4], t1[4], t2[4];
        #pragma unroll
        for (int t = 0; t < 2; ++t)
            #pragma unroll
            for (int r = 0; r < 4; ++r)
                x[t][r] = fmaxf(acc[u][t][r] + bias[t], 0.f);
        #pragma unroll
        for (int r = 0; r < 4; ++r) {
            t1[r] = x[0][r] + x[1][r];
            t2[r] = x[0][r] * x[0][r] + x[1][r] * x[1][r];
        }
        #pragma unroll
        for (int m = 1; m <= 8; m <<= 1) {
            #pragma unroll
            for (int r = 0; r < 4; ++r) {
                t1[r] += __shfl_xor(t1[r], m);
                t2[r] += __shfl_xor(t2[r], m);
            }
        }
        float z[2][4];
        #pragma unroll
        for (int r = 0; r < 4; ++r) {
            const float mu  = t1[r] * 0.03125f;
            const float var = fmaxf(t2[r] * 0.03125f - mu * mu, 0.f);
            const float inv = rsqrtf(var + 1e-5f);
            #pragma unroll
            for (int t = 0; t < 2; ++t)
                z[t][r] = (x[t][r] - mu) * inv * gam[t] + bet[t];
        }
        // softmax over k (4 regs in-lane x 4 lane-groups) fused with PV partial
        float S[2], o[2];
        #pragma unroll
        for (int t = 0; t < 2; ++t) {
            float mx = fmaxf(fmaxf(z[t][0], z[t][1]), fmaxf(z[t][2], z[t][3]));
            mx = fmaxf(mx, __shfl_xor(mx, 16));
            mx = fmaxf(mx, __shfl_xor(mx, 32));
            float s = 0.f, oo = 0.f;
            #pragma unroll
            for (int r = 0; r < 4; ++r) {
                const float p = __expf(z[t][r] - mx);
                s += p;
                oo = fmaf(p, vreg[u][t][r], oo);
            }
            s  += __shfl_xor(s, 16);
            s  += __shfl_xor(s, 32);
            oo += __shfl_xor(oo, 16);
            oo += __shfl_xor(oo, 32);
            S[t] = s; o[t] = oo;
        }
        if (l < 32) {  // e = l; half select by bit4
            const int   sel = lg & 1;
            const float os  = sel ? o[1] : o[0];
            const float ss  = sel ? S[1] : S[0];
            out[((size_t)n * HH + h0 + u) * DD + l] = __fdividef(os, ss);
        }
    }
}

extern "C" void kernel_launch(void* const* d_in, const int* in_sizes, int n_in,
                              void* d_out, int out_size, void* d_ws, size_t ws_size,
                              hipStream_t stream) {
    const float* q   = (const float*)d_in[0];
    const float* kn  = (const float*)d_in[1];
    const float* vn  = (const float*)d_in[2];
    const float* geo = (const float*)d_in[3];
    const float* W   = (const float*)d_in[4];
    const float* b   = (const float*)d_in[5];
    const float* gam = (const float*)d_in[6];
    const float* bet = (const float*)d_in[7];
    float* out = (float*)d_out;

    const int BN     = in_sizes[0] / (HH * DD);  // B*N
    const int waves  = BN * 2;                   // 2 units (h-pair) per wave
    const int blocks = (waves + 3) / 4;          // 4 waves per 256-thread block

    hipLaunchKernelGGL(geoneigh_mfma, dim3(blocks), dim3(256), 0, stream,
                       q, kn, vn, geo, W, b, gam, bet, out, BN);
}